// Round 7
// baseline (299.176 us; speedup 1.0000x reference)
//
#include <hip/hip_runtime.h>
#include <math.h>

#define BATCH 2048
#define DIN   784
#define HID   512
#define NC    10
#define NS    10

constexpr int HP  = HID + 1;        // 513
constexpr int M2  = NS * BATCH;     // 20480
constexpr int KP2 = 544;            // 513 padded to 17*32
constexpr int KP1 = 800;            // 784 padded to 25*32
constexpr int HROW = 544;           // padded h row length (bf16)

typedef __attribute__((ext_vector_type(8))) short          short8;
typedef __attribute__((ext_vector_type(8))) unsigned short ushort8;
typedef __attribute__((ext_vector_type(4))) float          floatx4;

__device__ inline unsigned short f2bf(float f) {
    unsigned u = __builtin_bit_cast(unsigned, f);
    u += 0x7FFFu + ((u >> 16) & 1u);
    return (unsigned short)(u >> 16);
}
__device__ inline float bf2f(unsigned short u) {
    return __builtin_bit_cast(float, (unsigned)u << 16);
}

// square each of 8 bf16 lanes; repack via v_perm_b32
__device__ inline short8 sq8(short8 a) {
    union { short8 s; unsigned u[4]; } x;
    x.s = a;
#pragma unroll
    for (int i = 0; i < 4; ++i) {
        unsigned t = x.u[i];
        float lo = __builtin_bit_cast(float, t << 16);
        float hi = __builtin_bit_cast(float, t & 0xFFFF0000u);
        unsigned lq = __builtin_bit_cast(unsigned, lo * lo);
        unsigned hq = __builtin_bit_cast(unsigned, hi * hi);
        x.u[i] = __builtin_amdgcn_perm(hq, lq, 0x07060302u);
    }
    return x.s;
}

#define GLOAD_LDS16(g, l)                                                      \
    __builtin_amdgcn_global_load_lds(                                          \
        (const __attribute__((address_space(1))) void*)(g),                    \
        (__attribute__((address_space(3))) void*)(l), 16, 0, 0)

// ---------------------------------------------------------------------------
// Dual MFMA GEMM, 128x64 block, 256 threads / 4 waves as 2x2, each wave a
// 64x32 output tile (4x2 16x16x32 frags): accm=A@Wm, accs=(A^2)@Ws2.
// Geometry rationale (R4 post-mortem):
//  - total regs/wave ~120 (56 VGPR + 64 AGPR acc) -> 3 waves/SIMD allowed;
//    this block is 4 waves, TILE 16KB tri-buffer 48KB -> 3 blocks/CU resident
//    (144KB LDS, 12 waves/CU) -- fits BOTH the register file and LDS.
//  - grid 8x160 = 1280 blocks on 768 slots: scheduling efficiency 83%
//    (R4: 640 blocks on 512 slots = 62.5%, a 128-block tail at 1/8 util).
//  - 64x32 wave tile: 8 ds_read_b128 per 16 dual-MFMAs = 0.031 B/FLOP
//    (32x64 tile was 0.038) -> per-CU LDS traffic drops ~20%.
// TRIPLE-buffered with counted vmcnt (T3/T4), 4 loads/thread/stage:
//   s_waitcnt vmcnt(4)  -- tile kt landed; tile kt+1's 4 loads stay in flight
//   s_barrier (certifies tile kt complete for ALL waves) + sched_barrier
//   stage(kt+2)         -- slot consumed in iter kt-1 (safe past barrier)
// XOR-swizzled via pre-swizzled global source (conflict-free ds_read_b128).
// XCD-chunked blockIdx swizzle keeps A row-panels L2-resident.
// ---------------------------------------------------------------------------
constexpr int TILE_B = 16384;   // A 8K + Bm 4K + Bs 4K

__global__ __launch_bounds__(256, 3)
void dual_gemm_mfma(const unsigned short* __restrict__ A,
                    const unsigned short* __restrict__ WTm,
                    const unsigned short* __restrict__ WTs2,
                    int Kp,
                    const float* __restrict__ eps,
                    unsigned short* __restrict__ hout,
                    float* __restrict__ mu_out,
                    float* __restrict__ sg_out)
{
    __shared__ __align__(16) char smem[3 * TILE_B];   // 48 KB tri-buffer

    const int tid  = threadIdx.x;
    const int lane = tid & 63;
    const int w    = tid >> 6;      // 0..3
    const int wr   = w >> 1;        // wave row (0..1) -> 64-row strip
    const int wc   = w & 1;         // wave col (0..1) -> 32-col strip
    const int quad = lane >> 4;
    const int l16  = lane & 15;

    // XCD-chunked bijective swizzle (gridDim.x == 8; nwg % 8 == 0)
    const int nwg = (int)(gridDim.x * gridDim.y);
    const int bid = (int)(blockIdx.y * gridDim.x + blockIdx.x);
    const int qch = nwg >> 3;
    const int lg  = (bid & 7) * qch + (bid >> 3);
    const int bx  = lg & 7;
    const int by  = lg >> 3;

    const int row0 = by * 128;
    const int col0 = bx * 64;

    const size_t KpB = (size_t)Kp * 2;
    const char* gA  = (const char*)A;
    const char* gBm = (const char*)WTm;
    const char* gBs = (const char*)WTs2;

    // staging: 256 threads; A = 128 rows x 64B (2 passes), B = 64 rows x 64B
    // per matrix (1 pass each).  4 x global_load_lds(16B) per thread.
    const int sr = tid >> 2;        // 0..63
    const int sq = tid & 3;
    auto stage = [&](int kt, char* buf) {
#pragma unroll
        for (int p = 0; p < 2; ++p) {
            const int row = sr + p * 64;
            const int qs  = sq ^ ((row >> 1) & 3);
            const size_t ka = (size_t)(row0 + row) * KpB + (size_t)kt * 64 + qs * 16;
            GLOAD_LDS16(gA + ka, buf + p * 4096 + tid * 16);
        }
        const int qs = sq ^ ((sr >> 1) & 3);
        const size_t kb = (size_t)(col0 + sr) * KpB + (size_t)kt * 64 + qs * 16;
        GLOAD_LDS16(gBm + kb, buf +  8192 + tid * 16);
        GLOAD_LDS16(gBs + kb, buf + 12288 + tid * 16);
    };

    // fragment LDS offsets (loop-invariant; include the read-side swizzle)
    int aoff[4], boff[2];
#pragma unroll
    for (int m = 0; m < 4; ++m) {
        const int row = wr * 64 + m * 16 + l16;
        aoff[m] = row * 64 + ((quad ^ ((row >> 1) & 3)) << 4);
    }
#pragma unroll
    for (int n = 0; n < 2; ++n) {
        const int row = wc * 32 + n * 16 + l16;
        boff[n] = 8192 + row * 64 + ((quad ^ ((row >> 1) & 3)) << 4);
    }

    floatx4 accm[4][2] = {};
    floatx4 accs[4][2] = {};

    const int ktiles = Kp >> 5;
    stage(0, smem);
    stage(1, smem + TILE_B);

    for (int kt = 0; kt < ktiles; ++kt) {
        // wait for own stage(kt); stage(kt+1)'s 4 loads stay in flight
        if (kt + 1 < ktiles) {
            asm volatile("s_waitcnt vmcnt(4)" ::: "memory");
        } else {
            asm volatile("s_waitcnt vmcnt(0)" ::: "memory");
        }
        __builtin_amdgcn_s_barrier();        // all waves' stage(kt) complete
        __builtin_amdgcn_sched_barrier(0);   // keep ds_reads below the barrier

        char* cur = smem + (kt % 3) * TILE_B;
        if (kt + 2 < ktiles) stage(kt + 2, smem + ((kt + 2) % 3) * TILE_B);

        short8 a[4], q8[4];
#pragma unroll
        for (int m = 0; m < 4; ++m) a[m] = *(const short8*)(cur + aoff[m]);
#pragma unroll
        for (int m = 0; m < 4; ++m) q8[m] = sq8(a[m]);

#pragma unroll
        for (int n = 0; n < 2; ++n) {
            const short8 bm = *(const short8*)(cur + boff[n]);
            const short8 bs = *(const short8*)(cur + boff[n] + 4096);
#pragma unroll
            for (int m = 0; m < 4; ++m) {
                accm[m][n] = __builtin_amdgcn_mfma_f32_16x16x32_bf16(a[m],  bm, accm[m][n], 0, 0, 0);
                accs[m][n] = __builtin_amdgcn_mfma_f32_16x16x32_bf16(q8[m], bs, accs[m][n], 0, 0, 0);
            }
        }
    }

    // epilogue: C/D layout col=lane&15, row=quad*4+reg
    const int erow = row0 + wr * 64 + quad * 4;
    const int ecol = col0 + wc * 32 + l16;
    if (eps != nullptr) {
        const float* gE = eps + (size_t)erow * HID + ecol;
        unsigned short* gH = hout + (size_t)erow * HROW + ecol;
#pragma unroll
        for (int m = 0; m < 4; ++m) {
#pragma unroll
            for (int n = 0; n < 2; ++n) {
                float e[4];
#pragma unroll
                for (int r = 0; r < 4; ++r)
                    e[r] = gE[(size_t)(m * 16 + r) * HID + n * 16];
#pragma unroll
                for (int r = 0; r < 4; ++r) {
                    const float sg = sqrtf(accs[m][n][r] + 1e-12f);
                    float v = accm[m][n][r] + sg * e[r];
                    v = v > 0.0f ? v : 0.01f * v;
                    gH[(size_t)(m * 16 + r) * HROW + n * 16] = f2bf(v);
                }
            }
        }
    } else {
        float* gM = mu_out + (size_t)erow * HID + ecol;
        float* gS = sg_out + (size_t)erow * HID + ecol;
#pragma unroll
        for (int m = 0; m < 4; ++m) {
#pragma unroll
            for (int n = 0; n < 2; ++n) {
#pragma unroll
                for (int r = 0; r < 4; ++r) {
                    const size_t o = (size_t)(m * 16 + r) * HID + n * 16;
                    gM[o] = accm[m][n][r];
                    gS[o] = sqrtf(accs[m][n][r] + 1e-12f);
                }
            }
        }
    }
}

// ---------------------------------------------------------------------------
// Weight pack: WTm[n][k] = bf16(Wm[k][n]); WTs2[n][k] = bf16((drop*Ws[k][n])^2)
// ---------------------------------------------------------------------------
__global__ __launch_bounds__(256)
void pack_wT(const float* __restrict__ Wm, const float* __restrict__ Ws,
             const float* __restrict__ dropPtr, int K, int Kp,
             unsigned short* __restrict__ WTm, unsigned short* __restrict__ WTs2)
{
    __shared__ float tm[32][33];
    __shared__ float ts[32][33];
    const float drop = dropPtr[0];
    const int k0 = blockIdx.x * 32, n0 = blockIdx.y * 32;
    const int tx = threadIdx.x, ty = threadIdx.y;   // 32 x 8
#pragma unroll
    for (int i = 0; i < 4; ++i) {
        const int k = k0 + ty + 8 * i;
        float m = 0.0f, s2 = 0.0f;
        if (k < K) {
            m = Wm[(size_t)k * HID + n0 + tx];
            const float s = Ws[(size_t)k * HID + n0 + tx] * drop;
            s2 = s * s;
        }
        tm[ty + 8 * i][tx] = m;
        ts[ty + 8 * i][tx] = s2;
    }
    __syncthreads();
#pragma unroll
    for (int i = 0; i < 4; ++i) {
        const int n = n0 + ty + 8 * i;
        WTm[(size_t)n * Kp + k0 + tx]  = f2bf(tm[tx][ty + 8 * i]);
        WTs2[(size_t)n * Kp + k0 + tx] = f2bf(ts[tx][ty + 8 * i]);
    }
}

// pack layer-4 weights: W4m[c][k] = bf16(mean[k][c]); W4s2[c][k] = bf16(scale[k][c]^2)
__global__ __launch_bounds__(256)
void pack_w4(const float* __restrict__ Wm, const float* __restrict__ Ws,
             unsigned short* __restrict__ W4m, unsigned short* __restrict__ W4s2)
{
    const int idx = blockIdx.x * 256 + threadIdx.x;   // 16*KP2
    if (idx >= 16 * KP2) return;
    const int c = idx / KP2;
    const int k = idx - c * KP2;
    float m = 0.0f, s2 = 0.0f;
    if (c < NC && k < HP) {
        m = Wm[(size_t)k * NC + c];
        const float s = Ws[(size_t)k * NC + c];
        s2 = s * s;
    }
    W4m[idx]  = f2bf(m);
    W4s2[idx] = f2bf(s2);
}

// convert inputs f32 [2048 x 784] -> bf16 [2048 x 800] zero-padded
__global__ __launch_bounds__(256)
void convert_x(const float* __restrict__ x, unsigned short* __restrict__ xb)
{
    const int idx = blockIdx.x * 256 + threadIdx.x;   // 2048*100
    if (idx >= BATCH * 100) return;
    const int r = idx / 100;
    const int c8 = (idx - r * 100) * 8;
    ushort8 o;
    if (c8 < DIN) {   // DIN=784=98*8
        const floatx4 a = *(const floatx4*)(x + (size_t)r * DIN + c8);
        const floatx4 b = *(const floatx4*)(x + (size_t)r * DIN + c8 + 4);
#pragma unroll
        for (int j = 0; j < 4; ++j) { o[j] = f2bf(a[j]); o[4 + j] = f2bf(b[j]); }
    } else {
#pragma unroll
        for (int j = 0; j < 8; ++j) o[j] = 0;
    }
    *(ushort8*)(xb + (size_t)r * KP1 + c8) = o;
}

// h1[r][c] = bf16(leaky(mu1[b][c] + sg1[b][c]*eps1[r][c])), full 544-row incl pad
__global__ __launch_bounds__(256)
void expand1(const float* __restrict__ mu1, const float* __restrict__ sg1,
             const float* __restrict__ eps1, unsigned short* __restrict__ h1)
{
    const int idx = blockIdx.x * 256 + threadIdx.x;   // M2*68
    if (idx >= M2 * 68) return;
    const int r  = idx / 68;
    const int c8 = (idx - r * 68) * 8;
    ushort8 o;
    if (c8 < HID) {
        const int b = r & (BATCH - 1);
        const floatx4* ep = (const floatx4*)(eps1 + (size_t)r * HID + c8);
        const floatx4* mp = (const floatx4*)(mu1 + (size_t)b * HID + c8);
        const floatx4* sp = (const floatx4*)(sg1 + (size_t)b * HID + c8);
        const floatx4 e0 = ep[0], e1 = ep[1];
        const floatx4 m0 = mp[0], m1 = mp[1];
        const floatx4 s0 = sp[0], s1 = sp[1];
#pragma unroll
        for (int j = 0; j < 4; ++j) {
            float v = m0[j] + s0[j] * e0[j];
            v = v > 0.0f ? v : 0.01f * v;
            o[j] = f2bf(v);
            float u = m1[j] + s1[j] * e1[j];
            u = u > 0.0f ? u : 0.01f * u;
            o[4 + j] = f2bf(u);
        }
    } else {
#pragma unroll
        for (int j = 0; j < 8; ++j) o[j] = 0;
        if (c8 == HID) o[0] = 0x3F80;   // bf16(1.0) ones column
    }
    *(ushort8*)(h1 + (size_t)r * HROW + c8) = o;
}

// pad columns 512..543 of an h buffer (ones col + zeros)
__global__ __launch_bounds__(256)
void pad_h(unsigned short* __restrict__ h)
{
    const int idx = blockIdx.x * 256 + threadIdx.x;   // M2*4
    if (idx >= M2 * 4) return;
    const int r = idx >> 2, seg = idx & 3;
    ushort8 o;
#pragma unroll
    for (int j = 0; j < 8; ++j) o[j] = 0;
    if (seg == 0) o[0] = 0x3F80;
    *(ushort8*)(h + (size_t)r * HROW + HID + seg * 8) = o;
}

// ---------------------------------------------------------------------------
// Layer 4 via MFMA + fused log_softmax.  [M2 x 544]bf16 @ [544 x 16]bf16.
// ---------------------------------------------------------------------------
__global__ __launch_bounds__(256)
void layer4_mfma(const unsigned short* __restrict__ h3,
                 const unsigned short* __restrict__ W4m,
                 const unsigned short* __restrict__ W4s2,
                 const float* __restrict__ eps4,
                 float* __restrict__ out)
{
    const int tid  = threadIdx.x;
    const int lane = tid & 63;
    const int w    = tid >> 6;
    const int quad = lane >> 4;
    const int l16  = lane & 15;

    const int row0 = (int)blockIdx.x * 64 + w * 16;   // 16 rows per wave

    const unsigned short* ha = h3  + (size_t)(row0 + l16) * HROW + quad * 8;
    const unsigned short* bm = W4m  + (size_t)l16 * KP2 + quad * 8;
    const unsigned short* bs = W4s2 + (size_t)l16 * KP2 + quad * 8;

    floatx4 accm = {}, accs = {};
#pragma unroll
    for (int kt = 0; kt < KP2 / 32; ++kt) {
        const short8 a  = *(const short8*)(ha + kt * 32);
        const short8 b1 = *(const short8*)(bm + kt * 32);
        const short8 b2 = *(const short8*)(bs + kt * 32);
        accm = __builtin_amdgcn_mfma_f32_16x16x32_bf16(a,      b1, accm, 0, 0, 0);
        accs = __builtin_amdgcn_mfma_f32_16x16x32_bf16(sq8(a), b2, accs, 0, 0, 0);
    }

    // epilogue: row = row0 + quad*4 + r, col = l16
    float lg[4];
#pragma unroll
    for (int r = 0; r < 4; ++r) {
        float v = -1e30f;
        if (l16 < NC) {
            const float e = eps4[(size_t)(row0 + quad * 4 + r) * NC + l16];
            v = accm[r] + sqrtf(accs[r] + 1e-12f) * e;
        }
        lg[r] = v;
    }
    float mx[4], sm[4];
#pragma unroll
    for (int r = 0; r < 4; ++r) mx[r] = lg[r];
#pragma unroll
    for (int off = 8; off; off >>= 1)
#pragma unroll
        for (int r = 0; r < 4; ++r) mx[r] = fmaxf(mx[r], __shfl_xor(mx[r], off, 64));
#pragma unroll
    for (int r = 0; r < 4; ++r) sm[r] = expf(lg[r] - mx[r]);   // invalid lanes -> 0
#pragma unroll
    for (int off = 8; off; off >>= 1)
#pragma unroll
        for (int r = 0; r < 4; ++r) sm[r] += __shfl_xor(sm[r], off, 64);
    if (l16 < NC) {
#pragma unroll
        for (int r = 0; r < 4; ++r)
            out[(size_t)(row0 + quad * 4 + r) * NC + l16] = lg[r] - (mx[r] + logf(sm[r]));
    }
}

// ---------------------------------------------------------------------------
extern "C" void kernel_launch(void* const* d_in, const int* in_sizes, int n_in,
                              void* d_out, int out_size, void* d_ws, size_t ws_size,
                              hipStream_t stream)
{
    const float* inputs   = (const float*)d_in[0];
    const float* a1_mean  = (const float*)d_in[1];
    const float* a1_scale = (const float*)d_in[2];
    const float* a1_drop  = (const float*)d_in[3];
    const float* a2_mean  = (const float*)d_in[4];
    const float* a2_scale = (const float*)d_in[5];
    const float* a2_drop  = (const float*)d_in[6];
    const float* a3_mean  = (const float*)d_in[7];
    const float* a3_scale = (const float*)d_in[8];
    const float* a3_drop  = (const float*)d_in[9];
    const float* a4_mean  = (const float*)d_in[10];
    const float* a4_scale = (const float*)d_in[11];
    const float* eps1     = (const float*)d_in[12];
    const float* eps2     = (const float*)d_in[13];
    const float* eps3     = (const float*)d_in[14];
    const float* eps4     = (const float*)d_in[15];
    float* out = (float*)d_out;

    char* p = (char*)d_ws;
    unsigned short* h_a  = (unsigned short*)p; p += (size_t)M2 * HROW * 2;
    unsigned short* h_b  = (unsigned short*)p; p += (size_t)M2 * HROW * 2;
    unsigned short* xb   = (unsigned short*)p; p += (size_t)BATCH * KP1 * 2;
    unsigned short* WT1m = (unsigned short*)p; p += (size_t)HID * KP1 * 2;
    unsigned short* WT1s = (unsigned short*)p; p += (size_t)HID * KP1 * 2;
    unsigned short* WT2m = (unsigned short*)p; p += (size_t)HID * KP2 * 2;
    unsigned short* WT2s = (unsigned short*)p; p += (size_t)HID * KP2 * 2;
    unsigned short* WT3m = (unsigned short*)p; p += (size_t)HID * KP2 * 2;
    unsigned short* WT3s = (unsigned short*)p; p += (size_t)HID * KP2 * 2;
    unsigned short* W4m  = (unsigned short*)p; p += (size_t)16 * KP2 * 2;
    unsigned short* W4s2 = (unsigned short*)p; p += (size_t)16 * KP2 * 2;
    float* mu1 = (float*)p; p += (size_t)BATCH * HID * 4;
    float* sg1 = (float*)p; p += (size_t)BATCH * HID * 4;

    // pack / convert
    convert_x<<<(BATCH * 100 + 255) / 256, 256, 0, stream>>>(inputs, xb);
    pack_wT<<<dim3(KP1 / 32, HID / 32), dim3(32, 8), 0, stream>>>(a1_mean, a1_scale, a1_drop, DIN, KP1, WT1m, WT1s);
    pack_wT<<<dim3(KP2 / 32, HID / 32), dim3(32, 8), 0, stream>>>(a2_mean, a2_scale, a2_drop, HP, KP2, WT2m, WT2s);
    pack_wT<<<dim3(KP2 / 32, HID / 32), dim3(32, 8), 0, stream>>>(a3_mean, a3_scale, a3_drop, HP, KP2, WT3m, WT3s);
    pack_w4<<<(16 * KP2 + 255) / 256, 256, 0, stream>>>(a4_mean, a4_scale, W4m, W4s2);
    pad_h<<<(M2 * 4 + 255) / 256, 256, 0, stream>>>(h_b);

    // layer 1 (sample-shared): mu1/sg1 [2048 x 512]
    dual_gemm_mfma<<<dim3(HID / 64, BATCH / 128), 256, 0, stream>>>(
        xb, WT1m, WT1s, KP1, nullptr, nullptr, mu1, sg1);

    // expand to h1 [20480 x 544] (incl ones + zero pad)
    expand1<<<(M2 * 68 + 255) / 256, 256, 0, stream>>>(mu1, sg1, eps1, h_a);

    // layer 2 fused -> h_b
    dual_gemm_mfma<<<dim3(HID / 64, M2 / 128), 256, 0, stream>>>(
        h_a, WT2m, WT2s, KP2, eps2, h_b, nullptr, nullptr);

    // layer 3 fused -> h_a (pad cols survive from expand1)
    dual_gemm_mfma<<<dim3(HID / 64, M2 / 128), 256, 0, stream>>>(
        h_b, WT3m, WT3s, KP2, eps3, h_a, nullptr, nullptr);

    // layer 4 MFMA + fused log_softmax
    layer4_mfma<<<M2 / 64, 256, 0, stream>>>(h_a, W4m, W4s2, eps4, out);
}

// Round 8
// 291.666 us; speedup vs baseline: 1.0257x; 1.0257x over previous
//
#include <hip/hip_runtime.h>
#include <math.h>

#define BATCH 2048
#define DIN   784
#define HID   512
#define NC    10
#define NS    10

constexpr int HP  = HID + 1;        // 513
constexpr int M2  = NS * BATCH;     // 20480
constexpr int KP2 = 544;            // 513 padded to 17*32
constexpr int KP1 = 800;            // 784 padded to 25*32
constexpr int HROW = 544;           // padded h row length (fp16)

typedef __attribute__((ext_vector_type(8))) _Float16       half8;
typedef __attribute__((ext_vector_type(8))) unsigned short ushort8;
typedef __attribute__((ext_vector_type(4))) float          floatx4;

__device__ inline unsigned short f2h(float f) {
    _Float16 h = (_Float16)f;
    return __builtin_bit_cast(unsigned short, h);
}

#define GLOAD_LDS16(g, l)                                                      \
    __builtin_amdgcn_global_load_lds(                                          \
        (const __attribute__((address_space(1))) void*)(g),                    \
        (__attribute__((address_space(3))) void*)(l), 16, 0, 0)

// ---------------------------------------------------------------------------
// Dual MFMA GEMM (fp16), 128x128 block, 512 threads / 8 waves as 4x2, each
// wave a 32x64 output tile (2x4 16x16x32 frags): accm=A@Wm, accs=(A^2)@Ws2.
// R7 post-mortem: VALUBusy 42% / MfmaUtil 15% -- the bf16 sq8 (per-element
// f32 mul + v_perm repack, ~80 VALU instr/wave/ktile) was the critical pipe.
// fp16 squaring is a*a on half8 = 4x v_pk_mul_f16; MFMA rate identical
// (mfma_f32_16x16x32_f16 = bf16 rate), precision better (10-bit mantissa,
// all values << 65k).  Geometry = R4's measured-best (52.5us) config.
// TRIPLE-buffered LDS (3 x 24KB) with counted vmcnt:
//   s_waitcnt vmcnt(3)  -- tile kt landed; tile kt+1's 3 loads stay in flight
//   s_barrier + sched_barrier(0)
//   stage(kt+2)         -- slot consumed in iter kt-1 (safe past barrier)
// XOR-swizzled via pre-swizzled global source (conflict-free ds_read_b128).
// XCD-chunked blockIdx swizzle keeps A row-panels L2-resident (FETCH ~40MB).
// ---------------------------------------------------------------------------
constexpr int TILE_B = 24576;   // A 8K + Bm 8K + Bs 8K

__global__ __launch_bounds__(512, 4)
void dual_gemm_mfma(const unsigned short* __restrict__ A,
                    const unsigned short* __restrict__ WTm,
                    const unsigned short* __restrict__ WTs2,
                    int Kp,
                    const float* __restrict__ eps,
                    unsigned short* __restrict__ hout,
                    float* __restrict__ mu_out,
                    float* __restrict__ sg_out)
{
    __shared__ __align__(16) char smem[3 * TILE_B];   // 72 KB tri-buffer

    const int tid  = threadIdx.x;
    const int lane = tid & 63;
    const int w    = tid >> 6;      // 0..7
    const int wr   = w >> 1;        // wave row (0..3) -> 32-row strip
    const int wc   = w & 1;         // wave col (0..1) -> 64-col strip
    const int quad = lane >> 4;
    const int l16  = lane & 15;

    // XCD-chunked bijective swizzle (nwg % 8 == 0 for all our grids)
    const int nwg = (int)(gridDim.x * gridDim.y);
    const int bid = (int)(blockIdx.y * gridDim.x + blockIdx.x);
    const int qch = nwg >> 3;
    const int lg  = (bid & 7) * qch + (bid >> 3);
    const int bx  = lg & 3;
    const int by  = lg >> 2;

    const int row0 = by * 128;
    const int col0 = bx * 128;

    const size_t KpB = (size_t)Kp * 2;
    const char* gA  = (const char*)A;
    const char* gBm = (const char*)WTm;
    const char* gBs = (const char*)WTs2;

    // staging: 512 threads cover 128 rows x 64B per matrix in ONE pass.
    const int sr = tid >> 2;        // 0..127
    const int sq = tid & 3;
    auto stage = [&](int kt, char* buf) {
        const int qs = sq ^ ((sr >> 1) & 3);
        const size_t ka = (size_t)(row0 + sr) * KpB + (size_t)kt * 64 + qs * 16;
        const size_t kb = (size_t)(col0 + sr) * KpB + (size_t)kt * 64 + qs * 16;
        GLOAD_LDS16(gA  + ka, buf +         tid * 16);
        GLOAD_LDS16(gBm + kb, buf +  8192 + tid * 16);
        GLOAD_LDS16(gBs + kb, buf + 16384 + tid * 16);
    };

    // fragment LDS offsets (loop-invariant; include the read-side swizzle)
    int aoff[2], boff[4];
#pragma unroll
    for (int m = 0; m < 2; ++m) {
        const int row = wr * 32 + m * 16 + l16;
        aoff[m] = row * 64 + ((quad ^ ((row >> 1) & 3)) << 4);
    }
#pragma unroll
    for (int n = 0; n < 4; ++n) {
        const int row = wc * 64 + n * 16 + l16;
        boff[n] = 8192 + row * 64 + ((quad ^ ((row >> 1) & 3)) << 4);
    }

    floatx4 accm[2][4] = {};
    floatx4 accs[2][4] = {};

    const int ktiles = Kp >> 5;
    stage(0, smem);
    stage(1, smem + TILE_B);

    for (int kt = 0; kt < ktiles; ++kt) {
        // wait for tile kt only; tile kt+1's 3 loads stay in flight
        if (kt + 1 < ktiles) {
            asm volatile("s_waitcnt vmcnt(3)" ::: "memory");
        } else {
            asm volatile("s_waitcnt vmcnt(0)" ::: "memory");
        }
        __builtin_amdgcn_s_barrier();        // all waves' stage(kt) complete
        __builtin_amdgcn_sched_barrier(0);   // keep ds_reads below the barrier

        char* cur = smem + (kt % 3) * TILE_B;
        if (kt + 2 < ktiles) stage(kt + 2, smem + ((kt + 2) % 3) * TILE_B);

        half8 a[2], q8[2];
#pragma unroll
        for (int m = 0; m < 2; ++m) a[m] = *(const half8*)(cur + aoff[m]);
#pragma unroll
        for (int m = 0; m < 2; ++m) q8[m] = a[m] * a[m];   // 4x v_pk_mul_f16

#pragma unroll
        for (int n = 0; n < 4; ++n) {
            const half8 bm = *(const half8*)(cur + boff[n]);
            const half8 bs = *(const half8*)(cur + boff[n] + 8192);
#pragma unroll
            for (int m = 0; m < 2; ++m) {
                accm[m][n] = __builtin_amdgcn_mfma_f32_16x16x32_f16(a[m],  bm, accm[m][n], 0, 0, 0);
                accs[m][n] = __builtin_amdgcn_mfma_f32_16x16x32_f16(q8[m], bs, accs[m][n], 0, 0, 0);
            }
        }
    }

    // epilogue: C/D layout col=lane&15, row=quad*4+reg
    const int erow = row0 + wr * 32 + quad * 4;
    const int ecol = col0 + wc * 64 + l16;
    if (eps != nullptr) {
        const float* gE = eps + (size_t)erow * HID + ecol;
        unsigned short* gH = hout + (size_t)erow * HROW + ecol;
#pragma unroll
        for (int m = 0; m < 2; ++m) {
#pragma unroll
            for (int n = 0; n < 4; ++n) {
                float e[4];
#pragma unroll
                for (int r = 0; r < 4; ++r)
                    e[r] = gE[(size_t)(m * 16 + r) * HID + n * 16];
#pragma unroll
                for (int r = 0; r < 4; ++r) {
                    const float sg = sqrtf(accs[m][n][r] + 1e-12f);
                    float v = accm[m][n][r] + sg * e[r];
                    v = v > 0.0f ? v : 0.01f * v;
                    gH[(size_t)(m * 16 + r) * HROW + n * 16] = f2h(v);
                }
            }
        }
    } else {
        float* gM = mu_out + (size_t)erow * HID + ecol;
        float* gS = sg_out + (size_t)erow * HID + ecol;
#pragma unroll
        for (int m = 0; m < 2; ++m) {
#pragma unroll
            for (int n = 0; n < 4; ++n) {
#pragma unroll
                for (int r = 0; r < 4; ++r) {
                    const size_t o = (size_t)(m * 16 + r) * HID + n * 16;
                    gM[o] = accm[m][n][r];
                    gS[o] = sqrtf(accs[m][n][r] + 1e-12f);
                }
            }
        }
    }
}

// ---------------------------------------------------------------------------
// Weight pack: WTm[n][k] = fp16(Wm[k][n]); WTs2[n][k] = fp16((drop*Ws[k][n])^2)
// ---------------------------------------------------------------------------
__global__ __launch_bounds__(256)
void pack_wT(const float* __restrict__ Wm, const float* __restrict__ Ws,
             const float* __restrict__ dropPtr, int K, int Kp,
             unsigned short* __restrict__ WTm, unsigned short* __restrict__ WTs2)
{
    __shared__ float tm[32][33];
    __shared__ float ts[32][33];
    const float drop = dropPtr[0];
    const int k0 = blockIdx.x * 32, n0 = blockIdx.y * 32;
    const int tx = threadIdx.x, ty = threadIdx.y;   // 32 x 8
#pragma unroll
    for (int i = 0; i < 4; ++i) {
        const int k = k0 + ty + 8 * i;
        float m = 0.0f, s2 = 0.0f;
        if (k < K) {
            m = Wm[(size_t)k * HID + n0 + tx];
            const float s = Ws[(size_t)k * HID + n0 + tx] * drop;
            s2 = s * s;
        }
        tm[ty + 8 * i][tx] = m;
        ts[ty + 8 * i][tx] = s2;
    }
    __syncthreads();
#pragma unroll
    for (int i = 0; i < 4; ++i) {
        const int n = n0 + ty + 8 * i;
        WTm[(size_t)n * Kp + k0 + tx]  = f2h(tm[tx][ty + 8 * i]);
        WTs2[(size_t)n * Kp + k0 + tx] = f2h(ts[tx][ty + 8 * i]);
    }
}

// pack layer-4 weights: W4m[c][k] = fp16(mean[k][c]); W4s2[c][k] = fp16(scale[k][c]^2)
__global__ __launch_bounds__(256)
void pack_w4(const float* __restrict__ Wm, const float* __restrict__ Ws,
             unsigned short* __restrict__ W4m, unsigned short* __restrict__ W4s2)
{
    const int idx = blockIdx.x * 256 + threadIdx.x;   // 16*KP2
    if (idx >= 16 * KP2) return;
    const int c = idx / KP2;
    const int k = idx - c * KP2;
    float m = 0.0f, s2 = 0.0f;
    if (c < NC && k < HP) {
        m = Wm[(size_t)k * NC + c];
        const float s = Ws[(size_t)k * NC + c];
        s2 = s * s;
    }
    W4m[idx]  = f2h(m);
    W4s2[idx] = f2h(s2);
}

// convert inputs f32 [2048 x 784] -> fp16 [2048 x 800] zero-padded
__global__ __launch_bounds__(256)
void convert_x(const float* __restrict__ x, unsigned short* __restrict__ xb)
{
    const int idx = blockIdx.x * 256 + threadIdx.x;   // 2048*100
    if (idx >= BATCH * 100) return;
    const int r = idx / 100;
    const int c8 = (idx - r * 100) * 8;
    ushort8 o;
    if (c8 < DIN) {   // DIN=784=98*8
        const floatx4 a = *(const floatx4*)(x + (size_t)r * DIN + c8);
        const floatx4 b = *(const floatx4*)(x + (size_t)r * DIN + c8 + 4);
#pragma unroll
        for (int j = 0; j < 4; ++j) { o[j] = f2h(a[j]); o[4 + j] = f2h(b[j]); }
    } else {
#pragma unroll
        for (int j = 0; j < 8; ++j) o[j] = 0;
    }
    *(ushort8*)(xb + (size_t)r * KP1 + c8) = o;
}

// h1[r][c] = fp16(leaky(mu1[b][c] + sg1[b][c]*eps1[r][c])), full 544-row incl pad
__global__ __launch_bounds__(256)
void expand1(const float* __restrict__ mu1, const float* __restrict__ sg1,
             const float* __restrict__ eps1, unsigned short* __restrict__ h1)
{
    const int idx = blockIdx.x * 256 + threadIdx.x;   // M2*68
    if (idx >= M2 * 68) return;
    const int r  = idx / 68;
    const int c8 = (idx - r * 68) * 8;
    ushort8 o;
    if (c8 < HID) {
        const int b = r & (BATCH - 1);
        const floatx4* ep = (const floatx4*)(eps1 + (size_t)r * HID + c8);
        const floatx4* mp = (const floatx4*)(mu1 + (size_t)b * HID + c8);
        const floatx4* sp = (const floatx4*)(sg1 + (size_t)b * HID + c8);
        const floatx4 e0 = ep[0], e1 = ep[1];
        const floatx4 m0 = mp[0], m1 = mp[1];
        const floatx4 s0 = sp[0], s1 = sp[1];
#pragma unroll
        for (int j = 0; j < 4; ++j) {
            float v = m0[j] + s0[j] * e0[j];
            v = v > 0.0f ? v : 0.01f * v;
            o[j] = f2h(v);
            float u = m1[j] + s1[j] * e1[j];
            u = u > 0.0f ? u : 0.01f * u;
            o[4 + j] = f2h(u);
        }
    } else {
#pragma unroll
        for (int j = 0; j < 8; ++j) o[j] = 0;
        if (c8 == HID) o[0] = 0x3C00;   // fp16(1.0) ones column
    }
    *(ushort8*)(h1 + (size_t)r * HROW + c8) = o;
}

// pad columns 512..543 of an h buffer (ones col + zeros)
__global__ __launch_bounds__(256)
void pad_h(unsigned short* __restrict__ h)
{
    const int idx = blockIdx.x * 256 + threadIdx.x;   // M2*4
    if (idx >= M2 * 4) return;
    const int r = idx >> 2, seg = idx & 3;
    ushort8 o;
#pragma unroll
    for (int j = 0; j < 8; ++j) o[j] = 0;
    if (seg == 0) o[0] = 0x3C00;   // fp16(1.0)
    *(ushort8*)(h + (size_t)r * HROW + HID + seg * 8) = o;
}

// ---------------------------------------------------------------------------
// Layer 4 via MFMA + fused log_softmax.  [M2 x 544]fp16 @ [544 x 16]fp16.
// ---------------------------------------------------------------------------
__global__ __launch_bounds__(256)
void layer4_mfma(const unsigned short* __restrict__ h3,
                 const unsigned short* __restrict__ W4m,
                 const unsigned short* __restrict__ W4s2,
                 const float* __restrict__ eps4,
                 float* __restrict__ out)
{
    const int tid  = threadIdx.x;
    const int lane = tid & 63;
    const int w    = tid >> 6;
    const int quad = lane >> 4;
    const int l16  = lane & 15;

    const int row0 = (int)blockIdx.x * 64 + w * 16;   // 16 rows per wave

    const unsigned short* ha = h3  + (size_t)(row0 + l16) * HROW + quad * 8;
    const unsigned short* bm = W4m  + (size_t)l16 * KP2 + quad * 8;
    const unsigned short* bs = W4s2 + (size_t)l16 * KP2 + quad * 8;

    floatx4 accm = {}, accs = {};
#pragma unroll
    for (int kt = 0; kt < KP2 / 32; ++kt) {
        const half8 a  = *(const half8*)(ha + kt * 32);
        const half8 b1 = *(const half8*)(bm + kt * 32);
        const half8 b2 = *(const half8*)(bs + kt * 32);
        accm = __builtin_amdgcn_mfma_f32_16x16x32_f16(a,     b1, accm, 0, 0, 0);
        accs = __builtin_amdgcn_mfma_f32_16x16x32_f16(a * a, b2, accs, 0, 0, 0);
    }

    // epilogue: row = row0 + quad*4 + r, col = l16
    float lg[4];
#pragma unroll
    for (int r = 0; r < 4; ++r) {
        float v = -1e30f;
        if (l16 < NC) {
            const float e = eps4[(size_t)(row0 + quad * 4 + r) * NC + l16];
            v = accm[r] + sqrtf(accs[r] + 1e-12f) * e;
        }
        lg[r] = v;
    }
    float mx[4], sm[4];
#pragma unroll
    for (int r = 0; r < 4; ++r) mx[r] = lg[r];
#pragma unroll
    for (int off = 8; off; off >>= 1)
#pragma unroll
        for (int r = 0; r < 4; ++r) mx[r] = fmaxf(mx[r], __shfl_xor(mx[r], off, 64));
#pragma unroll
    for (int r = 0; r < 4; ++r) sm[r] = expf(lg[r] - mx[r]);   // invalid lanes -> 0
#pragma unroll
    for (int off = 8; off; off >>= 1)
#pragma unroll
        for (int r = 0; r < 4; ++r) sm[r] += __shfl_xor(sm[r], off, 64);
    if (l16 < NC) {
#pragma unroll
        for (int r = 0; r < 4; ++r)
            out[(size_t)(row0 + quad * 4 + r) * NC + l16] = lg[r] - (mx[r] + logf(sm[r]));
    }
}

// ---------------------------------------------------------------------------
extern "C" void kernel_launch(void* const* d_in, const int* in_sizes, int n_in,
                              void* d_out, int out_size, void* d_ws, size_t ws_size,
                              hipStream_t stream)
{
    const float* inputs   = (const float*)d_in[0];
    const float* a1_mean  = (const float*)d_in[1];
    const float* a1_scale = (const float*)d_in[2];
    const float* a1_drop  = (const float*)d_in[3];
    const float* a2_mean  = (const float*)d_in[4];
    const float* a2_scale = (const float*)d_in[5];
    const float* a2_drop  = (const float*)d_in[6];
    const float* a3_mean  = (const float*)d_in[7];
    const float* a3_scale = (const float*)d_in[8];
    const float* a3_drop  = (const float*)d_in[9];
    const float* a4_mean  = (const float*)d_in[10];
    const float* a4_scale = (const float*)d_in[11];
    const float* eps1     = (const float*)d_in[12];
    const float* eps2     = (const float*)d_in[13];
    const float* eps3     = (const float*)d_in[14];
    const float* eps4     = (const float*)d_in[15];
    float* out = (float*)d_out;

    char* p = (char*)d_ws;
    unsigned short* h_a  = (unsigned short*)p; p += (size_t)M2 * HROW * 2;
    unsigned short* h_b  = (unsigned short*)p; p += (size_t)M2 * HROW * 2;
    unsigned short* xb   = (unsigned short*)p; p += (size_t)BATCH * KP1 * 2;
    unsigned short* WT1m = (unsigned short*)p; p += (size_t)HID * KP1 * 2;
    unsigned short* WT1s = (unsigned short*)p; p += (size_t)HID * KP1 * 2;
    unsigned short* WT2m = (unsigned short*)p; p += (size_t)HID * KP2 * 2;
    unsigned short* WT2s = (unsigned short*)p; p += (size_t)HID * KP2 * 2;
    unsigned short* WT3m = (unsigned short*)p; p += (size_t)HID * KP2 * 2;
    unsigned short* WT3s = (unsigned short*)p; p += (size_t)HID * KP2 * 2;
    unsigned short* W4m  = (unsigned short*)p; p += (size_t)16 * KP2 * 2;
    unsigned short* W4s2 = (unsigned short*)p; p += (size_t)16 * KP2 * 2;
    float* mu1 = (float*)p; p += (size_t)BATCH * HID * 4;
    float* sg1 = (float*)p; p += (size_t)BATCH * HID * 4;

    // pack / convert
    convert_x<<<(BATCH * 100 + 255) / 256, 256, 0, stream>>>(inputs, xb);
    pack_wT<<<dim3(KP1 / 32, HID / 32), dim3(32, 8), 0, stream>>>(a1_mean, a1_scale, a1_drop, DIN, KP1, WT1m, WT1s);
    pack_wT<<<dim3(KP2 / 32, HID / 32), dim3(32, 8), 0, stream>>>(a2_mean, a2_scale, a2_drop, HP, KP2, WT2m, WT2s);
    pack_wT<<<dim3(KP2 / 32, HID / 32), dim3(32, 8), 0, stream>>>(a3_mean, a3_scale, a3_drop, HP, KP2, WT3m, WT3s);
    pack_w4<<<(16 * KP2 + 255) / 256, 256, 0, stream>>>(a4_mean, a4_scale, W4m, W4s2);
    pad_h<<<(M2 * 4 + 255) / 256, 256, 0, stream>>>(h_b);

    // layer 1 (sample-shared): mu1/sg1 [2048 x 512]
    dual_gemm_mfma<<<dim3(HID / 128, BATCH / 128), 512, 0, stream>>>(
        xb, WT1m, WT1s, KP1, nullptr, nullptr, mu1, sg1);

    // expand to h1 [20480 x 544] (incl ones + zero pad)
    expand1<<<(M2 * 68 + 255) / 256, 256, 0, stream>>>(mu1, sg1, eps1, h_a);

    // layer 2 fused -> h_b
    dual_gemm_mfma<<<dim3(HID / 128, M2 / 128), 512, 0, stream>>>(
        h_a, WT2m, WT2s, KP2, eps2, h_b, nullptr, nullptr);

    // layer 3 fused -> h_a (pad cols survive from expand1)
    dual_gemm_mfma<<<dim3(HID / 128, M2 / 128), 512, 0, stream>>>(
        h_b, WT3m, WT3s, KP2, eps3, h_a, nullptr, nullptr);

    // layer 4 MFMA + fused log_softmax
    layer4_mfma<<<M2 / 64, 256, 0, stream>>>(h_a, W4m, W4s2, eps4, out);
}